// Round 1
// baseline (596.115 us; speedup 1.0000x reference)
//
#include <hip/hip_runtime.h>

// MeshUnpool: v = zeros(N,C); v[mask_idx] = img; then K sequential copies
//   for s in 0..K-1: k=K-1-s; v[order[1,k]] = v[order[0,k]]
// Resolved symbolically: final row r = initial row at root of the copy chain
// ending at the LAST step that wrote r. Initial row x = img[inv[x]] (or 0).
//
// Step-sequence indexing (s = execution order): f(s)=order[K-1-s], t(s)=order[K+K-1-s]

#define PAR_TILE 2048

__global__ void init_kernel(int* __restrict__ LW, int* __restrict__ inv, int N) {
    int r = blockIdx.x * blockDim.x + threadIdx.x;
    if (r < N) { LW[r] = -1; inv[r] = -1; }
}

__global__ void scatter_inv(const int* __restrict__ mask_idx, int* __restrict__ inv, int M) {
    int i = blockIdx.x * blockDim.x + threadIdx.x;
    if (i < M) inv[mask_idx[i]] = i;
}

// LW[r] = max step s with t(s)==r, else -1
__global__ void lw_kernel(const int* __restrict__ order, int K, int* __restrict__ LW) {
    int s = blockIdx.x * blockDim.x + threadIdx.x;
    if (s < K) {
        int t = order[K + (K - 1 - s)];
        atomicMax(&LW[t], s);
    }
}

// parent[s] = max s' < s with t(s')==f(s); parent[s]=s if none (root).
// LDS-tiled O(K^2) scan; blocks covering small s break out early.
__global__ void parent_kernel(const int* __restrict__ order, int K, int* __restrict__ parent) {
    __shared__ int t_tile[PAR_TILE];
    int s = blockIdx.x * blockDim.x + threadIdx.x;
    int f = (s < K) ? order[K - 1 - s] : -1;
    int best = -1;
    int blockEnd = blockIdx.x * blockDim.x + blockDim.x;  // exclusive upper s in block
    for (int base = 0; base < K; base += PAR_TILE) {
        if (base >= blockEnd) break;  // block-uniform: no s in this block needs later tiles
        __syncthreads();
        int n = min(PAR_TILE, K - base);
        for (int i = threadIdx.x; i < n; i += blockDim.x)
            t_tile[i] = order[K + (K - 1 - (base + i))];
        __syncthreads();
        int lim = min(n, s - base);  // enforce s' < s
        for (int i = 0; i < lim; ++i)
            if (t_tile[i] == f) best = base + i;
    }
    if (s < K) parent[s] = (best >= 0) ? best : s;
}

// RES[s] = source vertex feeding step s = f(root of parent-chain of s).
// Chains are expected-length ~0 (K^2/2N ~ 400 links among 20000 steps).
__global__ void res_kernel(const int* __restrict__ order, int K,
                           const int* __restrict__ parent, int* __restrict__ RES) {
    int s = blockIdx.x * blockDim.x + threadIdx.x;
    if (s >= K) return;
    int cur = s;
    int p = parent[cur];
    while (p != cur) { cur = p; p = parent[cur]; }
    RES[s] = order[K - 1 - cur];  // f(root): initial-content vertex
}

// out[r,:] = img[inv[src],:] or 0, src = (LW[r]<0) ? r : RES[LW[r]].
// float4-vectorized; C4 = C/4 lanes per row (pow2; C=128 -> c4shift=5).
__global__ void out_kernel(const float4* __restrict__ img4, const int* __restrict__ LW,
                           const int* __restrict__ inv, const int* __restrict__ RES,
                           float4* __restrict__ out4, int N, int c4shift) {
    int C4 = 1 << c4shift;
    int rowsPerBlock = blockDim.x >> c4shift;
    int row = blockIdx.x * rowsPerBlock + (threadIdx.x >> c4shift);
    int c4 = threadIdx.x & (C4 - 1);
    if (row >= N) return;
    int lw = LW[row];
    int src = (lw < 0) ? row : RES[lw];
    int j = inv[src];
    float4 val = make_float4(0.f, 0.f, 0.f, 0.f);
    if (j >= 0) val = img4[(long)j * C4 + c4];
    out4[(long)row * C4 + c4] = val;
}

extern "C" void kernel_launch(void* const* d_in, const int* in_sizes, int n_in,
                              void* d_out, int out_size, void* d_ws, size_t ws_size,
                              hipStream_t stream) {
    const float* img      = (const float*)d_in[0];
    const int*   mask_idx = (const int*)d_in[1];
    const int*   order    = (const int*)d_in[2];
    float*       out      = (float*)d_out;

    const int M  = in_sizes[1];            // 250000
    const int C  = in_sizes[0] / M;        // 128
    const int K  = in_sizes[2] / 2;        // 20000
    const int N  = out_size / C;           // 500000
    const int C4 = C / 4;                  // 32
    int c4shift = 0;
    while ((1 << c4shift) < C4) ++c4shift; // log2(C4); C4 is pow2 here

    int* LW     = (int*)d_ws;              // [N]
    int* inv    = LW + N;                  // [N]
    int* parent = inv + N;                 // [K]
    int* RES    = parent + K;              // [K]

    const int B = 256;

    init_kernel<<<(N + B - 1) / B, B, 0, stream>>>(LW, inv, N);
    scatter_inv<<<(M + B - 1) / B, B, 0, stream>>>(mask_idx, inv, M);
    lw_kernel<<<(K + B - 1) / B, B, 0, stream>>>(order, K, LW);
    parent_kernel<<<(K + B - 1) / B, B, 0, stream>>>(order, K, parent);
    res_kernel<<<(K + B - 1) / B, B, 0, stream>>>(order, K, parent, RES);

    int rowsPerBlock = B >> c4shift;       // 8 rows/block at C=128
    out_kernel<<<(N + rowsPerBlock - 1) / rowsPerBlock, B, 0, stream>>>(
        (const float4*)img, LW, inv, RES, (float4*)out, N, c4shift);
}

// Round 2
// 368.957 us; speedup vs baseline: 1.6157x; 1.6157x over previous
//
#include <hip/hip_runtime.h>

// MeshUnpool: v = zeros(N,C); v[mask_idx] = img; then K sequential copies
//   for s in 0..K-1: k=K-1-s; v[order[1,k]] = v[order[0,k]]
// Resolved symbolically: final row r = initial row at root of the copy chain
// ending at the LAST step that wrote r. Initial row x = img[inv[x]] (or 0).
//
// Step-sequence indexing (s = execution order): f(s)=order[K-1-s], t(s)=order[2K-1-s]
//
// R1: O(K^2) parent scan (240 us, 1.8% occupancy) replaced by per-vertex
// write chains via atomicExch — expected chain length K/N ~ 0.04.

__global__ void init_kernel(int* __restrict__ LW, int* __restrict__ inv,
                            int* __restrict__ head, int N) {
    int r = blockIdx.x * blockDim.x + threadIdx.x;
    if (r < N) { LW[r] = -1; inv[r] = -1; head[r] = -1; }
}

__global__ void scatter_inv(const int* __restrict__ mask_idx, int* __restrict__ inv, int M) {
    int i = blockIdx.x * blockDim.x + threadIdx.x;
    if (i < M) inv[mask_idx[i]] = i;
}

// LW[r] = max step s with t(s)==r; also build per-vertex write-chain:
// next[s] = previous head of t(s)'s list (unordered linked list of writes).
__global__ void lw_chain_kernel(const int* __restrict__ order, int K,
                                int* __restrict__ LW, int* __restrict__ head,
                                int* __restrict__ next) {
    int s = blockIdx.x * blockDim.x + threadIdx.x;
    if (s < K) {
        int t = order[2 * K - 1 - s];
        atomicMax(&LW[t], s);
        next[s] = atomicExch(&head[t], s);
    }
}

// parent[s] = max s' < s with t(s')==f(s); parent[s]=s if none (root).
// Walk f(s)'s write chain (expected length ~K/N).
__global__ void parent_kernel(const int* __restrict__ order, int K,
                              const int* __restrict__ head, const int* __restrict__ next,
                              int* __restrict__ parent) {
    int s = blockIdx.x * blockDim.x + threadIdx.x;
    if (s >= K) return;
    int f = order[K - 1 - s];
    int best = -1;
    for (int cur = head[f]; cur >= 0; cur = next[cur])
        if (cur < s && cur > best) best = cur;
    parent[s] = (best >= 0) ? best : s;
}

// RES[s] = source vertex feeding step s = f(root of parent-chain of s).
// Chains are expected-length ~0 (K^2/2N ~ 400 links among 20000 steps).
__global__ void res_kernel(const int* __restrict__ order, int K,
                           const int* __restrict__ parent, int* __restrict__ RES) {
    int s = blockIdx.x * blockDim.x + threadIdx.x;
    if (s >= K) return;
    int cur = s;
    int p = parent[cur];
    while (p != cur) { cur = p; p = parent[cur]; }
    RES[s] = order[K - 1 - cur];  // f(root): initial-content vertex
}

// out[r,:] = img[inv[src],:] or 0, src = (LW[r]<0) ? r : RES[LW[r]].
// float4-vectorized; C4 = C/4 lanes per row (pow2; C=128 -> c4shift=5).
__global__ void out_kernel(const float4* __restrict__ img4, const int* __restrict__ LW,
                           const int* __restrict__ inv, const int* __restrict__ RES,
                           float4* __restrict__ out4, int N, int c4shift) {
    int C4 = 1 << c4shift;
    int rowsPerBlock = blockDim.x >> c4shift;
    int row = blockIdx.x * rowsPerBlock + (threadIdx.x >> c4shift);
    int c4 = threadIdx.x & (C4 - 1);
    if (row >= N) return;
    int lw = LW[row];
    int src = (lw < 0) ? row : RES[lw];
    int j = inv[src];
    float4 val = make_float4(0.f, 0.f, 0.f, 0.f);
    if (j >= 0) val = img4[(long)j * C4 + c4];
    out4[(long)row * C4 + c4] = val;
}

extern "C" void kernel_launch(void* const* d_in, const int* in_sizes, int n_in,
                              void* d_out, int out_size, void* d_ws, size_t ws_size,
                              hipStream_t stream) {
    const float* img      = (const float*)d_in[0];
    const int*   mask_idx = (const int*)d_in[1];
    const int*   order    = (const int*)d_in[2];
    float*       out      = (float*)d_out;

    const int M  = in_sizes[1];            // 250000
    const int C  = in_sizes[0] / M;        // 128
    const int K  = in_sizes[2] / 2;        // 20000
    const int N  = out_size / C;           // 500000
    const int C4 = C / 4;                  // 32
    int c4shift = 0;
    while ((1 << c4shift) < C4) ++c4shift; // log2(C4); C4 is pow2 here

    int* LW     = (int*)d_ws;              // [N]
    int* inv    = LW + N;                  // [N]
    int* head   = inv + N;                 // [N]
    int* next   = head + N;                // [K]
    int* parent = next + K;                // [K]
    int* RES    = parent + K;              // [K]

    const int B = 256;

    init_kernel<<<(N + B - 1) / B, B, 0, stream>>>(LW, inv, head, N);
    scatter_inv<<<(M + B - 1) / B, B, 0, stream>>>(mask_idx, inv, M);
    lw_chain_kernel<<<(K + B - 1) / B, B, 0, stream>>>(order, K, LW, head, next);
    parent_kernel<<<(K + B - 1) / B, B, 0, stream>>>(order, K, head, next, parent);
    res_kernel<<<(K + B - 1) / B, B, 0, stream>>>(order, K, parent, RES);

    int rowsPerBlock = B >> c4shift;       // 8 rows/block at C=128
    out_kernel<<<(N + rowsPerBlock - 1) / rowsPerBlock, B, 0, stream>>>(
        (const float4*)img, LW, inv, RES, (float4*)out, N, c4shift);
}